// Round 2
// baseline (4493.061 us; speedup 1.0000x reference)
//
#include <hip/hip_runtime.h>
#include <hip/hip_bf16.h>

// N=200000, E=3200000, R=8, B=2, IN=128, H=32, OUT=128, U=10000, T=50000.

typedef float f4 __attribute__((ext_vector_type(4)));

// ---------------------------------------------------------------------------
// Basis projection + self-loop: one fused GEMM [N x DIN] @ [DIN x 96].
// cols 0..63 -> hb[n][64] (basis projections), cols 64..95 -> agg = h@loop + b.
// Each thread: 4 nodes x 4 cols register tile (16 independent accumulators).
// Weights in LDS (float4 reads); h rows read directly from global (float4,
// broadcast across the 24 col-group lanes -> few transactions, L1-served).
template<int DIN>
__global__ __launch_bounds__(192, 2)
void k_hb(const float* __restrict__ h, const float* __restrict__ V,
          const float* __restrict__ loopw, const float* __restrict__ bias,
          float* __restrict__ hb, float* __restrict__ agg, int nNodes)
{
    __shared__ float CW[DIN * 96];
    for (int idx = threadIdx.x; idx < DIN * 96; idx += 192) {
        int i = idx / 96, c = idx % 96;
        CW[idx] = (c < 64) ? V[(c >> 5) * DIN * 32 + i * 32 + (c & 31)]
                           : loopw[i * 32 + (c - 64)];
    }
    __syncthreads();

    const int cg = threadIdx.x % 24;   // column group: cols 4cg..4cg+3
    const int ng = threadIdx.x / 24;   // node group 0..7 -> 4 nodes each
    const int c0 = cg * 4;
    const int base = blockIdx.x * 32 + ng * 4;
    if (base >= nNodes) return;

    const float* hp[4];
    #pragma unroll
    for (int j = 0; j < 4; ++j)
        hp[j] = h + (long)min(base + j, nNodes - 1) * DIN;

    float acc[4][4] = {};
    for (int i = 0; i < DIN; i += 4) {
        f4 w0 = *(const f4*)&CW[(i + 0) * 96 + c0];
        f4 w1 = *(const f4*)&CW[(i + 1) * 96 + c0];
        f4 w2 = *(const f4*)&CW[(i + 2) * 96 + c0];
        f4 w3 = *(const f4*)&CW[(i + 3) * 96 + c0];
        #pragma unroll
        for (int j = 0; j < 4; ++j) {
            f4 hv = *(const f4*)(hp[j] + i);
            #pragma unroll
            for (int q = 0; q < 4; ++q)
                acc[j][q] = fmaf(hv[3], w3[q],
                            fmaf(hv[2], w2[q],
                            fmaf(hv[1], w1[q],
                            fmaf(hv[0], w0[q], acc[j][q]))));
        }
    }

    if (c0 < 64) {
        #pragma unroll
        for (int j = 0; j < 4; ++j) {
            if (base + j < nNodes) {
                f4 v = {acc[j][0], acc[j][1], acc[j][2], acc[j][3]};
                *(f4*)(hb + (long)(base + j) * 64 + c0) = v;
            }
        }
    } else {
        f4 bv = *(const f4*)(bias + (c0 - 64));
        #pragma unroll
        for (int j = 0; j < 4; ++j) {
            if (base + j < nNodes) {
                f4 v = {acc[j][0] + bv[0], acc[j][1] + bv[1],
                        acc[j][2] + bv[2], acc[j][3] + bv[3]};
                *(f4*)(agg + (long)(base + j) * 32 + (c0 - 64)) = v;
            }
        }
    }
}

// ---------------------------------------------------------------------------
// Edge message + scatter-add. 8 threads per edge, float4 gathers, 4 atomics.
__global__ __launch_bounds__(256)
void k_msg(const int* __restrict__ src, const int* __restrict__ dst,
           const int* __restrict__ et, const float* __restrict__ comb,
           const float* __restrict__ hb, float* __restrict__ agg, int nEdges)
{
    int gid = blockIdx.x * 256 + threadIdx.x;
    int e = gid >> 3;
    if (e >= nEdges) return;
    int o = (gid & 7) * 4;
    int s = src[e], d = dst[e], r = et[e];
    float c0 = comb[2 * r], c1 = comb[2 * r + 1];
    const f4 a = *(const f4*)(hb + (long)s * 64 + o);
    const f4 b = *(const f4*)(hb + (long)s * 64 + 32 + o);
    float* ap = agg + (long)d * 32 + o;
    atomicAdd(ap + 0, fmaf(c0, a[0], c1 * b[0]));
    atomicAdd(ap + 1, fmaf(c0, a[1], c1 * b[1]));
    atomicAdd(ap + 2, fmaf(c0, a[2], c1 * b[2]));
    atomicAdd(ap + 3, fmaf(c0, a[3], c1 * b[3]));
}

// ---------------------------------------------------------------------------
__global__ __launch_bounds__(256)
void k_tanh(float* __restrict__ p, int n)
{
    int i = blockIdx.x * 256 + threadIdx.x;
    if (i < n) p[i] = tanhf(p[i]);
}

// ---------------------------------------------------------------------------
// Fused MLP heads + reparameterization (unchanged — not a profile hotspot).
__global__ __launch_bounds__(256)
void k_mlp(const float* __restrict__ h0, const float* __restrict__ h1,
           const float* __restrict__ h2,
           const float* __restrict__ Wm1, const float* __restrict__ bm1,
           const float* __restrict__ Wm2, const float* __restrict__ bm2,
           const float* __restrict__ Ws1, const float* __restrict__ bs1,
           const float* __restrict__ Ws2, const float* __restrict__ bs2,
           const float* __restrict__ noise, float* __restrict__ z, int nNodes)
{
    __shared__ float sW1[2][96 * 32];
    __shared__ float sW2[2][32 * 128];
    __shared__ float sb1[2][32];
    __shared__ float sb2[2][128];
    __shared__ float shid[2][256];
    for (int i = threadIdx.x; i < 96 * 32; i += 256) { sW1[0][i] = Wm1[i]; sW1[1][i] = Ws1[i]; }
    for (int i = threadIdx.x; i < 32 * 128; i += 256) { sW2[0][i] = Wm2[i]; sW2[1][i] = Ws2[i]; }
    if (threadIdx.x < 32)  { sb1[0][threadIdx.x] = bm1[threadIdx.x]; sb1[1][threadIdx.x] = bs1[threadIdx.x]; }
    if (threadIdx.x < 128) { sb2[0][threadIdx.x] = bm2[threadIdx.x]; sb2[1][threadIdx.x] = bs2[threadIdx.x]; }
    __syncthreads();
    const int g = threadIdx.x >> 5;
    const int j = threadIdx.x & 31;
    for (int base = blockIdx.x * 8; base < nNodes; base += gridDim.x * 8) {
        int n = base + g;
        float hm = 0.f, hs = 0.f;
        if (n < nNodes) {
            const float* p0 = h0 + (long)n * 32;
            const float* p1 = h1 + (long)n * 32;
            const float* p2 = h2 + (long)n * 32;
            #pragma unroll 4
            for (int k = 0; k < 32; ++k) {
                float c = p0[k];
                hm = fmaf(c, sW1[0][k * 32 + j], hm);
                hs = fmaf(c, sW1[1][k * 32 + j], hs);
            }
            #pragma unroll 4
            for (int k = 0; k < 32; ++k) {
                float c = p1[k];
                hm = fmaf(c, sW1[0][(32 + k) * 32 + j], hm);
                hs = fmaf(c, sW1[1][(32 + k) * 32 + j], hs);
            }
            #pragma unroll 4
            for (int k = 0; k < 32; ++k) {
                float c = p2[k];
                hm = fmaf(c, sW1[0][(64 + k) * 32 + j], hm);
                hs = fmaf(c, sW1[1][(64 + k) * 32 + j], hs);
            }
        }
        hm = fmaxf(hm + sb1[0][j], 0.f);
        hs = fmaxf(hs + sb1[1][j], 0.f);
        __syncthreads();
        shid[0][threadIdx.x] = hm;
        shid[1][threadIdx.x] = hs;
        __syncthreads();
        if (n < nNodes) {
            float am[4] = {0.f, 0.f, 0.f, 0.f};
            float as_[4] = {0.f, 0.f, 0.f, 0.f};
            for (int k = 0; k < 32; ++k) {
                float vm = shid[0][g * 32 + k];
                float vs = shid[1][g * 32 + k];
                #pragma unroll
                for (int q = 0; q < 4; ++q) {
                    am[q]  = fmaf(vm, sW2[0][k * 128 + q * 32 + j], am[q]);
                    as_[q] = fmaf(vs, sW2[1][k * 128 + q * 32 + j], as_[q]);
                }
            }
            #pragma unroll
            for (int q = 0; q < 4; ++q) {
                int o = q * 32 + j;
                float mean = am[q] + sb2[0][o];
                float ls   = as_[q] + sb2[1][o];
                z[(long)n * 128 + o] = fmaf(noise[(long)n * 128 + o], expf(ls), mean);
            }
        }
    }
}

// ---------------------------------------------------------------------------
__global__ __launch_bounds__(256)
void k_pairs(const float* __restrict__ z, const int* __restrict__ ui,
             const int* __restrict__ ii, float* __restrict__ out, int U, int T)
{
    int w = (blockIdx.x * 256 + threadIdx.x) >> 6;
    int lane = threadIdx.x & 63;
    if (w >= U) return;
    int a = ui[w], b = ii[w];
    float a0 = z[(long)a * 128 + lane], a1 = z[(long)a * 128 + 64 + lane];
    float b0 = z[(long)b * 128 + lane], b1 = z[(long)b * 128 + 64 + lane];
    float* res = out + U + T;
    res[(long)w * 128 + lane] = a0;
    res[(long)w * 128 + 64 + lane] = a1;
    res[(long)(U + w) * 128 + lane] = b0;
    res[(long)(U + w) * 128 + 64 + lane] = b1;
    float d = fmaf(a0, b0, a1 * b1);
    #pragma unroll
    for (int off = 32; off; off >>= 1) d += __shfl_xor(d, off);
    if (lane == 0) out[w] = d;
}

__global__ __launch_bounds__(256)
void k_preds(const float* __restrict__ z, const int* __restrict__ ts,
             const int* __restrict__ td, float* __restrict__ out, int U, int T)
{
    int w = (blockIdx.x * 256 + threadIdx.x) >> 6;
    int lane = threadIdx.x & 63;
    if (w >= T) return;
    int a = ts[w], b = td[w];
    float a0 = z[(long)a * 128 + lane], a1 = z[(long)a * 128 + 64 + lane];
    float b0 = z[(long)b * 128 + lane], b1 = z[(long)b * 128 + 64 + lane];
    float d = fmaf(a0, b0, a1 * b1);
    #pragma unroll
    for (int off = 32; off; off >>= 1) d += __shfl_xor(d, off);
    if (lane == 0) out[U + w] = d;
}

// ---------------------------------------------------------------------------
extern "C" void kernel_launch(void* const* d_in, const int* in_sizes, int n_in,
                              void* d_out, int out_size, void* d_ws, size_t ws_size,
                              hipStream_t stream)
{
    const float* x     = (const float*)d_in[0];
    const int*   src   = (const int*)d_in[1];
    const int*   dst   = (const int*)d_in[2];
    const int*   et    = (const int*)d_in[3];
    const float* noise = (const float*)d_in[4];
    const int*   ui    = (const int*)d_in[5];
    const int*   ii    = (const int*)d_in[6];
    const int*   tes   = (const int*)d_in[7];
    const int*   ted   = (const int*)d_in[8];
    const float* V0    = (const float*)d_in[9];
    const float* comb0 = (const float*)d_in[10];
    const float* loop0 = (const float*)d_in[11];
    const float* b0    = (const float*)d_in[12];
    const float* V1    = (const float*)d_in[13];
    const float* comb1 = (const float*)d_in[14];
    const float* loop1 = (const float*)d_in[15];
    const float* b1    = (const float*)d_in[16];
    const float* V2    = (const float*)d_in[17];
    const float* comb2 = (const float*)d_in[18];
    const float* loop2 = (const float*)d_in[19];
    const float* b2    = (const float*)d_in[20];
    const float* Wm1   = (const float*)d_in[21];
    const float* bm1   = (const float*)d_in[22];
    const float* Wm2   = (const float*)d_in[23];
    const float* bm2   = (const float*)d_in[24];
    const float* Ws1   = (const float*)d_in[25];
    const float* bs1   = (const float*)d_in[26];
    const float* Ws2   = (const float*)d_in[27];
    const float* bs2   = (const float*)d_in[28];

    const int N = in_sizes[0] / 128;
    const int E = in_sizes[1];
    const int U = in_sizes[5];
    const int T = in_sizes[7];

    float* out = (float*)d_out;

    float* ws = (float*)d_ws;
    float* hb = ws;
    float* h0 = hb + (long)N * 64;
    float* h1 = h0 + (long)N * 32;
    float* h2 = h1 + (long)N * 32;
    float* z  = h2 + (long)N * 32;

    const int hbBlocks  = (N + 31) / 32;
    const int msgBlocks = (E * 8 + 255) / 256;
    const int ewBlocks  = (N * 32 + 255) / 256;

    // ---- layer 0 (din=128) ----
    k_hb<128><<<hbBlocks, 192, 0, stream>>>(x, V0, loop0, b0, hb, h0, N);
    k_msg<<<msgBlocks, 256, 0, stream>>>(src, dst, et, comb0, hb, h0, E);
    k_tanh<<<ewBlocks, 256, 0, stream>>>(h0, N * 32);
    // ---- layer 1 (din=32) ----
    k_hb<32><<<hbBlocks, 192, 0, stream>>>(h0, V1, loop1, b1, hb, h1, N);
    k_msg<<<msgBlocks, 256, 0, stream>>>(src, dst, et, comb1, hb, h1, E);
    k_tanh<<<ewBlocks, 256, 0, stream>>>(h1, N * 32);
    // ---- layer 2 (din=32) ----
    k_hb<32><<<hbBlocks, 192, 0, stream>>>(h1, V2, loop2, b2, hb, h2, N);
    k_msg<<<msgBlocks, 256, 0, stream>>>(src, dst, et, comb2, hb, h2, E);
    k_tanh<<<ewBlocks, 256, 0, stream>>>(h2, N * 32);
    // ---- heads + reparameterization ----
    k_mlp<<<2500, 256, 0, stream>>>(h0, h1, h2, Wm1, bm1, Wm2, bm2,
                                    Ws1, bs1, Ws2, bs2, noise, z, N);
    // ---- outputs ----
    k_pairs<<<(U * 64 + 255) / 256, 256, 0, stream>>>(z, ui, ii, out, U, T);
    k_preds<<<(T * 64 + 255) / 256, 256, 0, stream>>>(z, tes, ted, out, U, T);
}

// Round 3
// 1243.152 us; speedup vs baseline: 3.6142x; 3.6142x over previous
//
#include <hip/hip_runtime.h>
#include <hip/hip_bf16.h>

// N=200000, E=3200000, R=8, B=2, IN=128, H=32, OUT=128, U=10000, T=50000.

typedef float f4 __attribute__((ext_vector_type(4)));

// ---------------------------------------------------------------------------
// Layer-0 basis projection + self-loop GEMM: [N x 128] @ [128 x 96].
// cols 0..63 -> hb[n][64]; cols 64..95 -> h0[n][32] = x@loop + bias (agg init).
template<int DIN>
__global__ __launch_bounds__(192, 2)
void k_hb(const float* __restrict__ h, const float* __restrict__ V,
          const float* __restrict__ loopw, const float* __restrict__ bias,
          float* __restrict__ hb, float* __restrict__ agg, int nNodes)
{
    __shared__ float CW[DIN * 96];
    for (int idx = threadIdx.x; idx < DIN * 96; idx += 192) {
        int i = idx / 96, c = idx % 96;
        CW[idx] = (c < 64) ? V[(c >> 5) * DIN * 32 + i * 32 + (c & 31)]
                           : loopw[i * 32 + (c - 64)];
    }
    __syncthreads();

    const int cg = threadIdx.x % 24;
    const int ng = threadIdx.x / 24;
    const int c0 = cg * 4;
    const int base = blockIdx.x * 32 + ng * 4;
    if (base >= nNodes) return;

    const float* hp[4];
    #pragma unroll
    for (int j = 0; j < 4; ++j)
        hp[j] = h + (long)min(base + j, nNodes - 1) * DIN;

    float acc[4][4] = {};
    for (int i = 0; i < DIN; i += 4) {
        f4 w0 = *(const f4*)&CW[(i + 0) * 96 + c0];
        f4 w1 = *(const f4*)&CW[(i + 1) * 96 + c0];
        f4 w2 = *(const f4*)&CW[(i + 2) * 96 + c0];
        f4 w3 = *(const f4*)&CW[(i + 3) * 96 + c0];
        #pragma unroll
        for (int j = 0; j < 4; ++j) {
            f4 hv = *(const f4*)(hp[j] + i);
            #pragma unroll
            for (int q = 0; q < 4; ++q)
                acc[j][q] = fmaf(hv[3], w3[q],
                            fmaf(hv[2], w2[q],
                            fmaf(hv[1], w1[q],
                            fmaf(hv[0], w0[q], acc[j][q]))));
        }
    }

    if (c0 < 64) {
        #pragma unroll
        for (int j = 0; j < 4; ++j)
            if (base + j < nNodes) {
                f4 v = {acc[j][0], acc[j][1], acc[j][2], acc[j][3]};
                *(f4*)(hb + (long)(base + j) * 64 + c0) = v;
            }
    } else {
        f4 bv = *(const f4*)(bias + (c0 - 64));
        #pragma unroll
        for (int j = 0; j < 4; ++j)
            if (base + j < nNodes) {
                f4 v = {acc[j][0] + bv[0], acc[j][1] + bv[1],
                        acc[j][2] + bv[2], acc[j][3] + bv[3]};
                *(f4*)(agg + (long)(base + j) * 32 + (c0 - 64)) = v;
            }
    }
}

// ---------------------------------------------------------------------------
// CSR build: histogram, chunked scan, scatter.
__global__ __launch_bounds__(256)
void k_zeroi(int* __restrict__ p, int n)
{
    int i = blockIdx.x * 256 + threadIdx.x;
    if (i < n) p[i] = 0;
}

__global__ __launch_bounds__(256)
void k_count(const int* __restrict__ dst, int* __restrict__ dcnt, int nEdges)
{
    int e = blockIdx.x * 256 + threadIdx.x;
    if (e < nEdges) atomicAdd(&dcnt[dst[e]], 1);
}

// chunk = 512 elements; bsum[c] = sum of chunk c
__global__ __launch_bounds__(256)
void k_chunksum(const int* __restrict__ dcnt, int* __restrict__ bsum, int n)
{
    __shared__ int s[256];
    int base = blockIdx.x * 512, t = threadIdx.x;
    int v = 0;
    if (base + t < n)       v += dcnt[base + t];
    if (base + 256 + t < n) v += dcnt[base + 256 + t];
    s[t] = v; __syncthreads();
    for (int off = 128; off; off >>= 1) {
        if (t < off) s[t] += s[t + off];
        __syncthreads();
    }
    if (t == 0) bsum[blockIdx.x] = s[0];
}

// exclusive scan of bsum[nc] in a single block (nc <= 512)
__global__ __launch_bounds__(512)
void k_scanb(int* __restrict__ bsum, int nc)
{
    __shared__ int s[512];
    int t = threadIdx.x;
    int orig = (t < nc) ? bsum[t] : 0;
    s[t] = orig; __syncthreads();
    for (int off = 1; off < 512; off <<= 1) {
        int v = (t >= off) ? s[t - off] : 0;
        __syncthreads();
        s[t] += v;
        __syncthreads();
    }
    if (t < nc) bsum[t] = s[t] - orig;   // exclusive
}

// per-chunk scan + chunk offset -> rowptr & cursor (cursor may alias dcnt)
__global__ __launch_bounds__(512)
void k_scanc(const int* __restrict__ dcnt, const int* __restrict__ bsum,
             int* __restrict__ rowptr, int* __restrict__ cursor, int n, int nEdges)
{
    __shared__ int s[512];
    int t = threadIdx.x, i = blockIdx.x * 512 + t;
    int orig = (i < n) ? dcnt[i] : 0;
    s[t] = orig; __syncthreads();
    for (int off = 1; off < 512; off <<= 1) {
        int v = (t >= off) ? s[t - off] : 0;
        __syncthreads();
        s[t] += v;
        __syncthreads();
    }
    if (i < n) {
        int ex = bsum[blockIdx.x] + s[t] - orig;
        rowptr[i] = ex;
        cursor[i] = ex;
        if (i == n - 1) rowptr[n] = nEdges;
    }
}

__global__ __launch_bounds__(256)
void k_scatter(const int* __restrict__ src, const int* __restrict__ dst,
               const int* __restrict__ et, int* __restrict__ cursor,
               unsigned* __restrict__ packed, int nEdges)
{
    int e = blockIdx.x * 256 + threadIdx.x;
    if (e >= nEdges) return;
    int pos = atomicAdd(&cursor[dst[e]], 1);
    packed[pos] = ((unsigned)src[e] << 3) | (unsigned)et[e];
}

// ---------------------------------------------------------------------------
// Layer-0 pull: one wave per node, lanes 0..31 & 32..63 split the edge list.
// h0[n][o] = tanh(h0_selfloop[n][o] + sum_e c0*hb[s][o] + c1*hb[s][32+o])
__global__ __launch_bounds__(256)
void k_pull0(const int* __restrict__ rowptr, const unsigned* __restrict__ packed,
             const float* __restrict__ comb, const float* __restrict__ hb,
             float* __restrict__ h0, int nNodes)
{
    __shared__ float sc[16];
    if (threadIdx.x < 16) sc[threadIdx.x] = comb[threadIdx.x];
    __syncthreads();
    int n = blockIdx.x * 4 + (threadIdx.x >> 6);
    if (n >= nNodes) return;
    int lane = threadIdx.x & 63, o = lane & 31, half = lane >> 5;
    int beg = rowptr[n], end = rowptr[n + 1];
    float acc = 0.f;
    int j = beg + half;
    for (; j + 2 < end; j += 4) {            // 2 edges per iter per half
        unsigned pa = packed[j], pb = packed[j + 2];
        const float* ha = hb + (long)(pa >> 3) * 64;
        const float* hc = hb + (long)(pb >> 3) * 64;
        float a0 = ha[o], a1 = ha[32 + o];
        float b0 = hc[o], b1 = hc[32 + o];
        int ra = (pa & 7) * 2, rb = (pb & 7) * 2;
        acc = fmaf(sc[ra], a0, fmaf(sc[ra + 1], a1, acc));
        acc = fmaf(sc[rb], b0, fmaf(sc[rb + 1], b1, acc));
    }
    if (j < end) {
        unsigned pa = packed[j];
        const float* ha = hb + (long)(pa >> 3) * 64;
        int ra = (pa & 7) * 2;
        acc = fmaf(sc[ra], ha[o], fmaf(sc[ra + 1], ha[32 + o], acc));
    }
    acc += __shfl_xor(acc, 32);
    if (half == 0) {
        float* p = h0 + (long)n * 32 + o;
        *p = tanhf(*p + acc);
    }
}

// ---------------------------------------------------------------------------
// Layers 1/2 pull in INPUT space: u[n][b][i] = sum_e comb[r,b] * hsrc[s][i].
// Gathers 128B/edge instead of 256B.
__global__ __launch_bounds__(256)
void k_pull_u(const int* __restrict__ rowptr, const unsigned* __restrict__ packed,
              const float* __restrict__ comb, const float* __restrict__ hsrc,
              float* __restrict__ u, int nNodes)
{
    __shared__ float sc[16];
    if (threadIdx.x < 16) sc[threadIdx.x] = comb[threadIdx.x];
    __syncthreads();
    int n = blockIdx.x * 4 + (threadIdx.x >> 6);
    if (n >= nNodes) return;
    int lane = threadIdx.x & 63, i = lane & 31, half = lane >> 5;
    int beg = rowptr[n], end = rowptr[n + 1];
    float u0 = 0.f, u1 = 0.f;
    int j = beg + half;
    for (; j + 2 < end; j += 4) {
        unsigned pa = packed[j], pb = packed[j + 2];
        float ha = hsrc[(long)(pa >> 3) * 32 + i];
        float hc = hsrc[(long)(pb >> 3) * 32 + i];
        int ra = (pa & 7) * 2, rb = (pb & 7) * 2;
        u0 = fmaf(sc[ra], ha, u0);  u1 = fmaf(sc[ra + 1], ha, u1);
        u0 = fmaf(sc[rb], hc, u0);  u1 = fmaf(sc[rb + 1], hc, u1);
    }
    if (j < end) {
        unsigned pa = packed[j];
        float ha = hsrc[(long)(pa >> 3) * 32 + i];
        int ra = (pa & 7) * 2;
        u0 = fmaf(sc[ra], ha, u0);  u1 = fmaf(sc[ra + 1], ha, u1);
    }
    u0 += __shfl_xor(u0, 32);
    u1 += __shfl_xor(u1, 32);
    if (half == 0) {
        u[(long)n * 64 + i]      = u0;
        u[(long)n * 64 + 32 + i] = u1;
    }
}

// ---------------------------------------------------------------------------
// Post GEMM for layers 1/2: hdst = tanh([u0|u1|hsrc] @ [V0;V1;loop] + bias).
// 4 nodes x 4 cols per thread, weights (96x32) in LDS.
__global__ __launch_bounds__(256, 2)
void k_post(const float* __restrict__ u, const float* __restrict__ hsrc,
            const float* __restrict__ V, const float* __restrict__ loopw,
            const float* __restrict__ bias, float* __restrict__ hdst, int nNodes)
{
    __shared__ float CW[96 * 32];
    for (int idx = threadIdx.x; idx < 96 * 32; idx += 256) {
        int i = idx / 32, o = idx % 32;
        CW[idx] = (i < 64) ? V[i * 32 + o]            // V[b][k][o], b = i>>5
                           : loopw[(i - 64) * 32 + o];
    }
    __syncthreads();

    const int cg = threadIdx.x & 7;      // cols c0..c0+3
    const int ng = threadIdx.x >> 3;     // node group
    const int c0 = cg * 4;
    const int base = blockIdx.x * 128 + ng * 4;
    if (base >= nNodes) return;

    long rows[4];
    #pragma unroll
    for (int j = 0; j < 4; ++j)
        rows[j] = (long)min(base + j, nNodes - 1);

    float acc[4][4] = {};
    #pragma unroll 2
    for (int i = 0; i < 96; i += 4) {
        f4 w0 = *(const f4*)&CW[(i + 0) * 32 + c0];
        f4 w1 = *(const f4*)&CW[(i + 1) * 32 + c0];
        f4 w2 = *(const f4*)&CW[(i + 2) * 32 + c0];
        f4 w3 = *(const f4*)&CW[(i + 3) * 32 + c0];
        #pragma unroll
        for (int j = 0; j < 4; ++j) {
            f4 hv = (i < 64) ? *(const f4*)(u + rows[j] * 64 + i)
                             : *(const f4*)(hsrc + rows[j] * 32 + (i - 64));
            #pragma unroll
            for (int q = 0; q < 4; ++q)
                acc[j][q] = fmaf(hv[3], w3[q],
                            fmaf(hv[2], w2[q],
                            fmaf(hv[1], w1[q],
                            fmaf(hv[0], w0[q], acc[j][q]))));
        }
    }

    f4 bv = *(const f4*)(bias + c0);
    #pragma unroll
    for (int j = 0; j < 4; ++j)
        if (base + j < nNodes) {
            f4 v = {tanhf(acc[j][0] + bv[0]), tanhf(acc[j][1] + bv[1]),
                    tanhf(acc[j][2] + bv[2]), tanhf(acc[j][3] + bv[3])};
            *(f4*)(hdst + (long)(base + j) * 32 + c0) = v;
        }
}

// ---------------------------------------------------------------------------
// Fused MLP heads + reparameterization.
__global__ __launch_bounds__(256)
void k_mlp(const float* __restrict__ h0, const float* __restrict__ h1,
           const float* __restrict__ h2,
           const float* __restrict__ Wm1, const float* __restrict__ bm1,
           const float* __restrict__ Wm2, const float* __restrict__ bm2,
           const float* __restrict__ Ws1, const float* __restrict__ bs1,
           const float* __restrict__ Ws2, const float* __restrict__ bs2,
           const float* __restrict__ noise, float* __restrict__ z, int nNodes)
{
    __shared__ float sW1[2][96 * 32];
    __shared__ float sW2[2][32 * 128];
    __shared__ float sb1[2][32];
    __shared__ float sb2[2][128];
    __shared__ float shid[2][256];
    for (int i = threadIdx.x; i < 96 * 32; i += 256) { sW1[0][i] = Wm1[i]; sW1[1][i] = Ws1[i]; }
    for (int i = threadIdx.x; i < 32 * 128; i += 256) { sW2[0][i] = Wm2[i]; sW2[1][i] = Ws2[i]; }
    if (threadIdx.x < 32)  { sb1[0][threadIdx.x] = bm1[threadIdx.x]; sb1[1][threadIdx.x] = bs1[threadIdx.x]; }
    if (threadIdx.x < 128) { sb2[0][threadIdx.x] = bm2[threadIdx.x]; sb2[1][threadIdx.x] = bs2[threadIdx.x]; }
    __syncthreads();
    const int g = threadIdx.x >> 5;
    const int j = threadIdx.x & 31;
    for (int base = blockIdx.x * 8; base < nNodes; base += gridDim.x * 8) {
        int n = base + g;
        float hm = 0.f, hs = 0.f;
        if (n < nNodes) {
            const float* p0 = h0 + (long)n * 32;
            const float* p1 = h1 + (long)n * 32;
            const float* p2 = h2 + (long)n * 32;
            #pragma unroll 4
            for (int k = 0; k < 32; ++k) {
                float c = p0[k];
                hm = fmaf(c, sW1[0][k * 32 + j], hm);
                hs = fmaf(c, sW1[1][k * 32 + j], hs);
            }
            #pragma unroll 4
            for (int k = 0; k < 32; ++k) {
                float c = p1[k];
                hm = fmaf(c, sW1[0][(32 + k) * 32 + j], hm);
                hs = fmaf(c, sW1[1][(32 + k) * 32 + j], hs);
            }
            #pragma unroll 4
            for (int k = 0; k < 32; ++k) {
                float c = p2[k];
                hm = fmaf(c, sW1[0][(64 + k) * 32 + j], hm);
                hs = fmaf(c, sW1[1][(64 + k) * 32 + j], hs);
            }
        }
        hm = fmaxf(hm + sb1[0][j], 0.f);
        hs = fmaxf(hs + sb1[1][j], 0.f);
        __syncthreads();
        shid[0][threadIdx.x] = hm;
        shid[1][threadIdx.x] = hs;
        __syncthreads();
        if (n < nNodes) {
            float am[4] = {0.f, 0.f, 0.f, 0.f};
            float as_[4] = {0.f, 0.f, 0.f, 0.f};
            for (int k = 0; k < 32; ++k) {
                float vm = shid[0][g * 32 + k];
                float vs = shid[1][g * 32 + k];
                #pragma unroll
                for (int q = 0; q < 4; ++q) {
                    am[q]  = fmaf(vm, sW2[0][k * 128 + q * 32 + j], am[q]);
                    as_[q] = fmaf(vs, sW2[1][k * 128 + q * 32 + j], as_[q]);
                }
            }
            #pragma unroll
            for (int q = 0; q < 4; ++q) {
                int o = q * 32 + j;
                float mean = am[q] + sb2[0][o];
                float ls   = as_[q] + sb2[1][o];
                z[(long)n * 128 + o] = fmaf(noise[(long)n * 128 + o], expf(ls), mean);
            }
        }
    }
}

// ---------------------------------------------------------------------------
__global__ __launch_bounds__(256)
void k_pairs(const float* __restrict__ z, const int* __restrict__ ui,
             const int* __restrict__ ii, float* __restrict__ out, int U, int T)
{
    int w = (blockIdx.x * 256 + threadIdx.x) >> 6;
    int lane = threadIdx.x & 63;
    if (w >= U) return;
    int a = ui[w], b = ii[w];
    float a0 = z[(long)a * 128 + lane], a1 = z[(long)a * 128 + 64 + lane];
    float b0 = z[(long)b * 128 + lane], b1 = z[(long)b * 128 + 64 + lane];
    float* res = out + U + T;
    res[(long)w * 128 + lane] = a0;
    res[(long)w * 128 + 64 + lane] = a1;
    res[(long)(U + w) * 128 + lane] = b0;
    res[(long)(U + w) * 128 + 64 + lane] = b1;
    float d = fmaf(a0, b0, a1 * b1);
    #pragma unroll
    for (int off = 32; off; off >>= 1) d += __shfl_xor(d, off);
    if (lane == 0) out[w] = d;
}

__global__ __launch_bounds__(256)
void k_preds(const float* __restrict__ z, const int* __restrict__ ts,
             const int* __restrict__ td, float* __restrict__ out, int U, int T)
{
    int w = (blockIdx.x * 256 + threadIdx.x) >> 6;
    int lane = threadIdx.x & 63;
    if (w >= T) return;
    int a = ts[w], b = td[w];
    float a0 = z[(long)a * 128 + lane], a1 = z[(long)a * 128 + 64 + lane];
    float b0 = z[(long)b * 128 + lane], b1 = z[(long)b * 128 + 64 + lane];
    float d = fmaf(a0, b0, a1 * b1);
    #pragma unroll
    for (int off = 32; off; off >>= 1) d += __shfl_xor(d, off);
    if (lane == 0) out[U + w] = d;
}

// ---------------------------------------------------------------------------
extern "C" void kernel_launch(void* const* d_in, const int* in_sizes, int n_in,
                              void* d_out, int out_size, void* d_ws, size_t ws_size,
                              hipStream_t stream)
{
    const float* x     = (const float*)d_in[0];
    const int*   src   = (const int*)d_in[1];
    const int*   dst   = (const int*)d_in[2];
    const int*   et    = (const int*)d_in[3];
    const float* noise = (const float*)d_in[4];
    const int*   ui    = (const int*)d_in[5];
    const int*   ii    = (const int*)d_in[6];
    const int*   tes   = (const int*)d_in[7];
    const int*   ted   = (const int*)d_in[8];
    const float* V0    = (const float*)d_in[9];
    const float* comb0 = (const float*)d_in[10];
    const float* loop0 = (const float*)d_in[11];
    const float* b0    = (const float*)d_in[12];
    const float* V1    = (const float*)d_in[13];
    const float* comb1 = (const float*)d_in[14];
    const float* loop1 = (const float*)d_in[15];
    const float* b1    = (const float*)d_in[16];
    const float* V2    = (const float*)d_in[17];
    const float* comb2 = (const float*)d_in[18];
    const float* loop2 = (const float*)d_in[19];
    const float* b2    = (const float*)d_in[20];
    const float* Wm1   = (const float*)d_in[21];
    const float* bm1   = (const float*)d_in[22];
    const float* Wm2   = (const float*)d_in[23];
    const float* bm2   = (const float*)d_in[24];
    const float* Ws1   = (const float*)d_in[25];
    const float* bs1   = (const float*)d_in[26];
    const float* Ws2   = (const float*)d_in[27];
    const float* bs2   = (const float*)d_in[28];

    const int N = in_sizes[0] / 128;   // 200000
    const int E = in_sizes[1];         // 3200000
    const int U = in_sizes[5];
    const int T = in_sizes[7];

    float* out = (float*)d_out;

    // Workspace (floats): hb/u[N*64] | h0[N*32] | h1 | h2 | z[N*128]
    // Int CSR scratch aliases the z region (z is only written after the last
    // use of the CSR arrays; k_mlp -> z overwrites them harmlessly).
    float* ws = (float*)d_ws;
    float* hb = ws;                       // also the 'u' buffer for layers 1/2
    float* h0 = hb + (long)N * 64;
    float* h1 = h0 + (long)N * 32;
    float* h2 = h1 + (long)N * 32;
    float* z  = h2 + (long)N * 32;
    int*      dcnt   = (int*)z;           // N   (reused as cursor)
    int*      rowptr = dcnt + N;          // N+1
    unsigned* packed = (unsigned*)(rowptr + N + 1);   // E
    int*      bsum   = (int*)(packed + E);            // nchunks
    int*      cursor = dcnt;

    const int nchunks   = (N + 511) / 512;            // 391
    const int eBlocks   = (E + 255) / 256;
    const int hbBlocks  = (N + 31) / 32;
    const int pullBlocks = (N + 3) / 4;
    const int postBlocks = (N + 127) / 128;

    // ---- CSR build (by dst), reused for all 3 layers ----
    k_zeroi<<<(N + 255) / 256, 256, 0, stream>>>(dcnt, N);
    k_count<<<eBlocks, 256, 0, stream>>>(dst, dcnt, E);
    k_chunksum<<<nchunks, 256, 0, stream>>>(dcnt, bsum, N);
    k_scanb<<<1, 512, 0, stream>>>(bsum, nchunks);
    k_scanc<<<nchunks, 512, 0, stream>>>(dcnt, bsum, rowptr, cursor, N, E);
    k_scatter<<<eBlocks, 256, 0, stream>>>(src, dst, et, cursor, packed, E);

    // ---- layer 0: basis GEMM + self-loop init, then pull + tanh ----
    k_hb<128><<<hbBlocks, 192, 0, stream>>>(x, V0, loop0, b0, hb, h0, N);
    k_pull0<<<pullBlocks, 256, 0, stream>>>(rowptr, packed, comb0, hb, h0, N);

    // ---- layer 1: input-space pull, then fused GEMM+selfloop+tanh ----
    k_pull_u<<<pullBlocks, 256, 0, stream>>>(rowptr, packed, comb1, h0, hb, N);
    k_post<<<postBlocks, 256, 0, stream>>>(hb, h0, V1, loop1, b1, h1, N);

    // ---- layer 2 ----
    k_pull_u<<<pullBlocks, 256, 0, stream>>>(rowptr, packed, comb2, h1, hb, N);
    k_post<<<postBlocks, 256, 0, stream>>>(hb, h1, V2, loop2, b2, h2, N);

    // ---- heads + reparameterization ----
    k_mlp<<<2500, 256, 0, stream>>>(h0, h1, h2, Wm1, bm1, Wm2, bm2,
                                    Ws1, bs1, Ws2, bs2, noise, z, N);
    // ---- outputs ----
    k_pairs<<<(U * 64 + 255) / 256, 256, 0, stream>>>(z, ui, ii, out, U, T);
    k_preds<<<(T * 64 + 255) / 256, 256, 0, stream>>>(z, tes, ted, out, U, T);
}

// Round 4
// 1069.911 us; speedup vs baseline: 4.1995x; 1.1619x over previous
//
#include <hip/hip_runtime.h>
#include <hip/hip_bf16.h>

// N=200000, E=3200000, R=8, B=2, IN=128, H=32, OUT=128, U=10000, T=50000.

typedef float f4 __attribute__((ext_vector_type(4)));

// ---------------------------------------------------------------------------
// Layer-0 basis projection + self-loop GEMM: [N x 128] @ [128 x 96].
// cols 0..63 -> hb[n][64]; cols 64..95 -> h0[n][32] = x@loop + bias (agg init).
template<int DIN>
__global__ __launch_bounds__(192, 2)
void k_hb(const float* __restrict__ h, const float* __restrict__ V,
          const float* __restrict__ loopw, const float* __restrict__ bias,
          float* __restrict__ hb, float* __restrict__ agg, int nNodes)
{
    __shared__ float CW[DIN * 96];
    for (int idx = threadIdx.x; idx < DIN * 96; idx += 192) {
        int i = idx / 96, c = idx % 96;
        CW[idx] = (c < 64) ? V[(c >> 5) * DIN * 32 + i * 32 + (c & 31)]
                           : loopw[i * 32 + (c - 64)];
    }
    __syncthreads();

    const int cg = threadIdx.x % 24;
    const int ng = threadIdx.x / 24;
    const int c0 = cg * 4;
    const int base = blockIdx.x * 32 + ng * 4;
    if (base >= nNodes) return;

    const float* hp[4];
    #pragma unroll
    for (int j = 0; j < 4; ++j)
        hp[j] = h + (long)min(base + j, nNodes - 1) * DIN;

    float acc[4][4] = {};
    for (int i = 0; i < DIN; i += 4) {
        f4 w0 = *(const f4*)&CW[(i + 0) * 96 + c0];
        f4 w1 = *(const f4*)&CW[(i + 1) * 96 + c0];
        f4 w2 = *(const f4*)&CW[(i + 2) * 96 + c0];
        f4 w3 = *(const f4*)&CW[(i + 3) * 96 + c0];
        #pragma unroll
        for (int j = 0; j < 4; ++j) {
            f4 hv = *(const f4*)(hp[j] + i);
            #pragma unroll
            for (int q = 0; q < 4; ++q)
                acc[j][q] = fmaf(hv[3], w3[q],
                            fmaf(hv[2], w2[q],
                            fmaf(hv[1], w1[q],
                            fmaf(hv[0], w0[q], acc[j][q]))));
        }
    }

    if (c0 < 64) {
        #pragma unroll
        for (int j = 0; j < 4; ++j)
            if (base + j < nNodes) {
                f4 v = {acc[j][0], acc[j][1], acc[j][2], acc[j][3]};
                *(f4*)(hb + (long)(base + j) * 64 + c0) = v;
            }
    } else {
        f4 bv = *(const f4*)(bias + (c0 - 64));
        #pragma unroll
        for (int j = 0; j < 4; ++j)
            if (base + j < nNodes) {
                f4 v = {acc[j][0] + bv[0], acc[j][1] + bv[1],
                        acc[j][2] + bv[2], acc[j][3] + bv[3]};
                *(f4*)(agg + (long)(base + j) * 32 + (c0 - 64)) = v;
            }
    }
}

// ---------------------------------------------------------------------------
// CSR build: histogram, chunked scan, scatter.
__global__ __launch_bounds__(256)
void k_zeroi(int* __restrict__ p, int n)
{
    int i = blockIdx.x * 256 + threadIdx.x;
    if (i < n) p[i] = 0;
}

__global__ __launch_bounds__(256)
void k_count(const int* __restrict__ dst, int* __restrict__ dcnt, int nEdges)
{
    int e = blockIdx.x * 256 + threadIdx.x;
    if (e < nEdges) atomicAdd(&dcnt[dst[e]], 1);
}

__global__ __launch_bounds__(256)
void k_chunksum(const int* __restrict__ dcnt, int* __restrict__ bsum, int n)
{
    __shared__ int s[256];
    int base = blockIdx.x * 512, t = threadIdx.x;
    int v = 0;
    if (base + t < n)       v += dcnt[base + t];
    if (base + 256 + t < n) v += dcnt[base + 256 + t];
    s[t] = v; __syncthreads();
    for (int off = 128; off; off >>= 1) {
        if (t < off) s[t] += s[t + off];
        __syncthreads();
    }
    if (t == 0) bsum[blockIdx.x] = s[0];
}

__global__ __launch_bounds__(512)
void k_scanb(int* __restrict__ bsum, int nc)
{
    __shared__ int s[512];
    int t = threadIdx.x;
    int orig = (t < nc) ? bsum[t] : 0;
    s[t] = orig; __syncthreads();
    for (int off = 1; off < 512; off <<= 1) {
        int v = (t >= off) ? s[t - off] : 0;
        __syncthreads();
        s[t] += v;
        __syncthreads();
    }
    if (t < nc) bsum[t] = s[t] - orig;   // exclusive
}

__global__ __launch_bounds__(512)
void k_scanc(const int* __restrict__ dcnt, const int* __restrict__ bsum,
             int* __restrict__ rowptr, int* __restrict__ cursor, int n, int nEdges)
{
    __shared__ int s[512];
    int t = threadIdx.x, i = blockIdx.x * 512 + t;
    int orig = (i < n) ? dcnt[i] : 0;
    s[t] = orig; __syncthreads();
    for (int off = 1; off < 512; off <<= 1) {
        int v = (t >= off) ? s[t - off] : 0;
        __syncthreads();
        s[t] += v;
        __syncthreads();
    }
    if (i < n) {
        int ex = bsum[blockIdx.x] + s[t] - orig;
        rowptr[i] = ex;
        cursor[i] = ex;
        if (i == n - 1) rowptr[n] = nEdges;
    }
}

__global__ __launch_bounds__(256)
void k_scatter(const int* __restrict__ src, const int* __restrict__ dst,
               const int* __restrict__ et, int* __restrict__ cursor,
               unsigned* __restrict__ packed, int nEdges)
{
    int e = blockIdx.x * 256 + threadIdx.x;
    if (e >= nEdges) return;
    int pos = atomicAdd(&cursor[dst[e]], 1);
    packed[pos] = ((unsigned)src[e] << 3) | (unsigned)et[e];
}

// ---------------------------------------------------------------------------
// Layer-0 pull: one wave per node, lanes 0..31 & 32..63 split the edge list.
__global__ __launch_bounds__(256)
void k_pull0(const int* __restrict__ rowptr, const unsigned* __restrict__ packed,
             const float* __restrict__ comb, const float* __restrict__ hb,
             float* __restrict__ h0, int nNodes)
{
    __shared__ float sc[16];
    if (threadIdx.x < 16) sc[threadIdx.x] = comb[threadIdx.x];
    __syncthreads();
    int n = blockIdx.x * 4 + (threadIdx.x >> 6);
    if (n >= nNodes) return;
    int lane = threadIdx.x & 63, o = lane & 31, half = lane >> 5;
    int beg = rowptr[n], end = rowptr[n + 1];
    float acc = 0.f;
    int j = beg + half;
    for (; j + 2 < end; j += 4) {
        unsigned pa = packed[j], pb = packed[j + 2];
        const float* ha = hb + (long)(pa >> 3) * 64;
        const float* hc = hb + (long)(pb >> 3) * 64;
        float a0 = ha[o], a1 = ha[32 + o];
        float b0 = hc[o], b1 = hc[32 + o];
        int ra = (pa & 7) * 2, rb = (pb & 7) * 2;
        acc = fmaf(sc[ra], a0, fmaf(sc[ra + 1], a1, acc));
        acc = fmaf(sc[rb], b0, fmaf(sc[rb + 1], b1, acc));
    }
    if (j < end) {
        unsigned pa = packed[j];
        const float* ha = hb + (long)(pa >> 3) * 64;
        int ra = (pa & 7) * 2;
        acc = fmaf(sc[ra], ha[o], fmaf(sc[ra + 1], ha[32 + o], acc));
    }
    acc += __shfl_xor(acc, 32);
    if (half == 0) {
        float* p = h0 + (long)n * 32 + o;
        *p = tanhf(*p + acc);
    }
}

// ---------------------------------------------------------------------------
// Layers 1/2 pull in INPUT space: u[n][b][i] = sum_e comb[r,b] * hsrc[s][i].
__global__ __launch_bounds__(256)
void k_pull_u(const int* __restrict__ rowptr, const unsigned* __restrict__ packed,
              const float* __restrict__ comb, const float* __restrict__ hsrc,
              float* __restrict__ u, int nNodes)
{
    __shared__ float sc[16];
    if (threadIdx.x < 16) sc[threadIdx.x] = comb[threadIdx.x];
    __syncthreads();
    int n = blockIdx.x * 4 + (threadIdx.x >> 6);
    if (n >= nNodes) return;
    int lane = threadIdx.x & 63, i = lane & 31, half = lane >> 5;
    int beg = rowptr[n], end = rowptr[n + 1];
    float u0 = 0.f, u1 = 0.f;
    int j = beg + half;
    for (; j + 2 < end; j += 4) {
        unsigned pa = packed[j], pb = packed[j + 2];
        float ha = hsrc[(long)(pa >> 3) * 32 + i];
        float hc = hsrc[(long)(pb >> 3) * 32 + i];
        int ra = (pa & 7) * 2, rb = (pb & 7) * 2;
        u0 = fmaf(sc[ra], ha, u0);  u1 = fmaf(sc[ra + 1], ha, u1);
        u0 = fmaf(sc[rb], hc, u0);  u1 = fmaf(sc[rb + 1], hc, u1);
    }
    if (j < end) {
        unsigned pa = packed[j];
        float ha = hsrc[(long)(pa >> 3) * 32 + i];
        int ra = (pa & 7) * 2;
        u0 = fmaf(sc[ra], ha, u0);  u1 = fmaf(sc[ra + 1], ha, u1);
    }
    u0 += __shfl_xor(u0, 32);
    u1 += __shfl_xor(u1, 32);
    if (half == 0) {
        u[(long)n * 64 + i]      = u0;
        u[(long)n * 64 + 32 + i] = u1;
    }
}

// ---------------------------------------------------------------------------
// Post GEMM for layers 1/2: hdst = tanh([u0|u1|hsrc] @ [V0;V1;loop] + bias).
__global__ __launch_bounds__(256, 2)
void k_post(const float* __restrict__ u, const float* __restrict__ hsrc,
            const float* __restrict__ V, const float* __restrict__ loopw,
            const float* __restrict__ bias, float* __restrict__ hdst, int nNodes)
{
    __shared__ float CW[96 * 32];
    for (int idx = threadIdx.x; idx < 96 * 32; idx += 256) {
        int i = idx / 32, o = idx % 32;
        CW[idx] = (i < 64) ? V[i * 32 + o]
                           : loopw[(i - 64) * 32 + o];
    }
    __syncthreads();

    const int cg = threadIdx.x & 7;
    const int ng = threadIdx.x >> 3;
    const int c0 = cg * 4;
    const int base = blockIdx.x * 128 + ng * 4;
    if (base >= nNodes) return;

    long rows[4];
    #pragma unroll
    for (int j = 0; j < 4; ++j)
        rows[j] = (long)min(base + j, nNodes - 1);

    float acc[4][4] = {};
    #pragma unroll 2
    for (int i = 0; i < 96; i += 4) {
        f4 w0 = *(const f4*)&CW[(i + 0) * 32 + c0];
        f4 w1 = *(const f4*)&CW[(i + 1) * 32 + c0];
        f4 w2 = *(const f4*)&CW[(i + 2) * 32 + c0];
        f4 w3 = *(const f4*)&CW[(i + 3) * 32 + c0];
        #pragma unroll
        for (int j = 0; j < 4; ++j) {
            f4 hv = (i < 64) ? *(const f4*)(u + rows[j] * 64 + i)
                             : *(const f4*)(hsrc + rows[j] * 32 + (i - 64));
            #pragma unroll
            for (int q = 0; q < 4; ++q)
                acc[j][q] = fmaf(hv[3], w3[q],
                            fmaf(hv[2], w2[q],
                            fmaf(hv[1], w1[q],
                            fmaf(hv[0], w0[q], acc[j][q]))));
        }
    }

    f4 bv = *(const f4*)(bias + c0);
    #pragma unroll
    for (int j = 0; j < 4; ++j)
        if (base + j < nNodes) {
            f4 v = {tanhf(acc[j][0] + bv[0]), tanhf(acc[j][1] + bv[1]),
                    tanhf(acc[j][2] + bv[2]), tanhf(acc[j][3] + bv[3])};
            *(f4*)(hdst + (long)(base + j) * 32 + c0) = v;
        }
}

// ---------------------------------------------------------------------------
// Fused MLP heads + reparameterization, register-tiled.
// Block = 64-node tile. Phase A: threads 0-127 mean head, 128-255 std head,
// each thread 4 nodes x 4 hidden cols -> shid. Phase B: 2 passes of 32 nodes,
// each thread 4 nodes x 4 out cols, both heads, fused exp/noise/z-store.
__global__ __launch_bounds__(256, 2)
void k_mlp(const float* __restrict__ h0, const float* __restrict__ h1,
           const float* __restrict__ h2,
           const float* __restrict__ Wm1, const float* __restrict__ bm1,
           const float* __restrict__ Wm2, const float* __restrict__ bm2,
           const float* __restrict__ Ws1, const float* __restrict__ bs1,
           const float* __restrict__ Ws2, const float* __restrict__ bs2,
           const float* __restrict__ noise, float* __restrict__ z, int nNodes)
{
    __shared__ float sW1[2][96 * 32];
    __shared__ float sW2[2][32 * 128];
    __shared__ float sb1[2][32];
    __shared__ float sb2[2][128];
    __shared__ float shid[2][64][32];

    for (int i = threadIdx.x; i < 96 * 32; i += 256) { sW1[0][i] = Wm1[i]; sW1[1][i] = Ws1[i]; }
    for (int i = threadIdx.x; i < 32 * 128; i += 256) { sW2[0][i] = Wm2[i]; sW2[1][i] = Ws2[i]; }
    if (threadIdx.x < 32)  { sb1[0][threadIdx.x] = bm1[threadIdx.x]; sb1[1][threadIdx.x] = bs1[threadIdx.x]; }
    if (threadIdx.x < 128) { sb2[0][threadIdx.x] = bm2[threadIdx.x]; sb2[1][threadIdx.x] = bs2[threadIdx.x]; }
    __syncthreads();

    const int base = blockIdx.x * 64;
    if (base >= nNodes) return;

    // ---- phase A: hidden = relu(cs @ W1 + b1) ----
    {
        const int head = threadIdx.x >> 7;     // 0: mean, 1: std
        const int rem  = threadIdx.x & 127;
        const int ng   = rem >> 3;             // 0..15 -> 4 nodes each
        const int c0   = (rem & 7) * 4;        // hidden cols c0..c0+3
        const float* sW = sW1[head];
        long rows[4];
        #pragma unroll
        for (int j = 0; j < 4; ++j)
            rows[j] = (long)min(base + ng * 4 + j, nNodes - 1);

        float acc[4][4] = {};
        const float* hs[3] = {h0, h1, h2};
        #pragma unroll
        for (int part = 0; part < 3; ++part) {
            const float* hp = hs[part];
            #pragma unroll
            for (int kk = 0; kk < 32; kk += 4) {
                const int k = part * 32 + kk;
                f4 w0 = *(const f4*)&sW[(k + 0) * 32 + c0];
                f4 w1 = *(const f4*)&sW[(k + 1) * 32 + c0];
                f4 w2 = *(const f4*)&sW[(k + 2) * 32 + c0];
                f4 w3 = *(const f4*)&sW[(k + 3) * 32 + c0];
                #pragma unroll
                for (int j = 0; j < 4; ++j) {
                    f4 hv = *(const f4*)(hp + rows[j] * 32 + kk);
                    #pragma unroll
                    for (int q = 0; q < 4; ++q)
                        acc[j][q] = fmaf(hv[3], w3[q],
                                    fmaf(hv[2], w2[q],
                                    fmaf(hv[1], w1[q],
                                    fmaf(hv[0], w0[q], acc[j][q]))));
                }
            }
        }
        f4 bv = *(const f4*)&sb1[head][c0];
        #pragma unroll
        for (int j = 0; j < 4; ++j) {
            f4 v = {fmaxf(acc[j][0] + bv[0], 0.f), fmaxf(acc[j][1] + bv[1], 0.f),
                    fmaxf(acc[j][2] + bv[2], 0.f), fmaxf(acc[j][3] + bv[3], 0.f)};
            *(f4*)&shid[head][ng * 4 + j][c0] = v;
        }
    }
    __syncthreads();

    // ---- phase B: out = hid @ W2 + b2; z = mean + noise * exp(log_std) ----
    const int ng = threadIdx.x >> 5;           // 0..7 -> 4 nodes each
    const int c0 = (threadIdx.x & 31) * 4;     // out cols c0..c0+3
    #pragma unroll
    for (int pass = 0; pass < 2; ++pass) {
        const int nb = pass * 32 + ng * 4;     // local node base
        float am[4][4] = {}, as_[4][4] = {};
        #pragma unroll 4
        for (int k = 0; k < 32; k += 4) {
            f4 wm0 = *(const f4*)&sW2[0][(k + 0) * 128 + c0];
            f4 wm1 = *(const f4*)&sW2[0][(k + 1) * 128 + c0];
            f4 wm2 = *(const f4*)&sW2[0][(k + 2) * 128 + c0];
            f4 wm3 = *(const f4*)&sW2[0][(k + 3) * 128 + c0];
            f4 ws0 = *(const f4*)&sW2[1][(k + 0) * 128 + c0];
            f4 ws1 = *(const f4*)&sW2[1][(k + 1) * 128 + c0];
            f4 ws2 = *(const f4*)&sW2[1][(k + 2) * 128 + c0];
            f4 ws3 = *(const f4*)&sW2[1][(k + 3) * 128 + c0];
            #pragma unroll
            for (int j = 0; j < 4; ++j) {
                f4 hm = *(const f4*)&shid[0][nb + j][k];
                f4 hv = *(const f4*)&shid[1][nb + j][k];
                #pragma unroll
                for (int q = 0; q < 4; ++q) {
                    am[j][q]  = fmaf(hm[3], wm3[q],
                                fmaf(hm[2], wm2[q],
                                fmaf(hm[1], wm1[q],
                                fmaf(hm[0], wm0[q], am[j][q]))));
                    as_[j][q] = fmaf(hv[3], ws3[q],
                                fmaf(hv[2], ws2[q],
                                fmaf(hv[1], ws1[q],
                                fmaf(hv[0], ws0[q], as_[j][q]))));
                }
            }
        }
        f4 b2m = *(const f4*)&sb2[0][c0];
        f4 b2s = *(const f4*)&sb2[1][c0];
        #pragma unroll
        for (int j = 0; j < 4; ++j) {
            const int n = base + nb + j;
            if (n < nNodes) {
                f4 nz = *(const f4*)(noise + (long)n * 128 + c0);
                f4 v;
                #pragma unroll
                for (int q = 0; q < 4; ++q)
                    v[q] = fmaf(nz[q], expf(as_[j][q] + b2s[q]), am[j][q] + b2m[q]);
                *(f4*)(z + (long)n * 128 + c0) = v;
            }
        }
    }
}

// ---------------------------------------------------------------------------
__global__ __launch_bounds__(256)
void k_pairs(const float* __restrict__ z, const int* __restrict__ ui,
             const int* __restrict__ ii, float* __restrict__ out, int U, int T)
{
    int w = (blockIdx.x * 256 + threadIdx.x) >> 6;
    int lane = threadIdx.x & 63;
    if (w >= U) return;
    int a = ui[w], b = ii[w];
    float a0 = z[(long)a * 128 + lane], a1 = z[(long)a * 128 + 64 + lane];
    float b0 = z[(long)b * 128 + lane], b1 = z[(long)b * 128 + 64 + lane];
    float* res = out + U + T;
    res[(long)w * 128 + lane] = a0;
    res[(long)w * 128 + 64 + lane] = a1;
    res[(long)(U + w) * 128 + lane] = b0;
    res[(long)(U + w) * 128 + 64 + lane] = b1;
    float d = fmaf(a0, b0, a1 * b1);
    #pragma unroll
    for (int off = 32; off; off >>= 1) d += __shfl_xor(d, off);
    if (lane == 0) out[w] = d;
}

__global__ __launch_bounds__(256)
void k_preds(const float* __restrict__ z, const int* __restrict__ ts,
             const int* __restrict__ td, float* __restrict__ out, int U, int T)
{
    int w = (blockIdx.x * 256 + threadIdx.x) >> 6;
    int lane = threadIdx.x & 63;
    if (w >= T) return;
    int a = ts[w], b = td[w];
    float a0 = z[(long)a * 128 + lane], a1 = z[(long)a * 128 + 64 + lane];
    float b0 = z[(long)b * 128 + lane], b1 = z[(long)b * 128 + 64 + lane];
    float d = fmaf(a0, b0, a1 * b1);
    #pragma unroll
    for (int off = 32; off; off >>= 1) d += __shfl_xor(d, off);
    if (lane == 0) out[U + w] = d;
}

// ---------------------------------------------------------------------------
extern "C" void kernel_launch(void* const* d_in, const int* in_sizes, int n_in,
                              void* d_out, int out_size, void* d_ws, size_t ws_size,
                              hipStream_t stream)
{
    const float* x     = (const float*)d_in[0];
    const int*   src   = (const int*)d_in[1];
    const int*   dst   = (const int*)d_in[2];
    const int*   et    = (const int*)d_in[3];
    const float* noise = (const float*)d_in[4];
    const int*   ui    = (const int*)d_in[5];
    const int*   ii    = (const int*)d_in[6];
    const int*   tes   = (const int*)d_in[7];
    const int*   ted   = (const int*)d_in[8];
    const float* V0    = (const float*)d_in[9];
    const float* comb0 = (const float*)d_in[10];
    const float* loop0 = (const float*)d_in[11];
    const float* b0    = (const float*)d_in[12];
    const float* V1    = (const float*)d_in[13];
    const float* comb1 = (const float*)d_in[14];
    const float* loop1 = (const float*)d_in[15];
    const float* b1    = (const float*)d_in[16];
    const float* V2    = (const float*)d_in[17];
    const float* comb2 = (const float*)d_in[18];
    const float* loop2 = (const float*)d_in[19];
    const float* b2    = (const float*)d_in[20];
    const float* Wm1   = (const float*)d_in[21];
    const float* bm1   = (const float*)d_in[22];
    const float* Wm2   = (const float*)d_in[23];
    const float* bm2   = (const float*)d_in[24];
    const float* Ws1   = (const float*)d_in[25];
    const float* bs1   = (const float*)d_in[26];
    const float* Ws2   = (const float*)d_in[27];
    const float* bs2   = (const float*)d_in[28];

    const int N = in_sizes[0] / 128;   // 200000
    const int E = in_sizes[1];         // 3200000
    const int U = in_sizes[5];
    const int T = in_sizes[7];

    float* out = (float*)d_out;

    // Workspace (floats): hb/u[N*64] | h0[N*32] | h1 | h2 | z[N*128]
    // Int CSR scratch aliases the z region (freed before k_mlp writes z).
    float* ws = (float*)d_ws;
    float* hb = ws;
    float* h0 = hb + (long)N * 64;
    float* h1 = h0 + (long)N * 32;
    float* h2 = h1 + (long)N * 32;
    float* z  = h2 + (long)N * 32;
    int*      dcnt   = (int*)z;
    int*      rowptr = dcnt + N;
    unsigned* packed = (unsigned*)(rowptr + N + 1);
    int*      bsum   = (int*)(packed + E);
    int*      cursor = dcnt;

    const int nchunks    = (N + 511) / 512;
    const int eBlocks    = (E + 255) / 256;
    const int hbBlocks   = (N + 31) / 32;
    const int pullBlocks = (N + 3) / 4;
    const int postBlocks = (N + 127) / 128;
    const int mlpBlocks  = (N + 63) / 64;

    // ---- CSR build (by dst), reused for all 3 layers ----
    k_zeroi<<<(N + 255) / 256, 256, 0, stream>>>(dcnt, N);
    k_count<<<eBlocks, 256, 0, stream>>>(dst, dcnt, E);
    k_chunksum<<<nchunks, 256, 0, stream>>>(dcnt, bsum, N);
    k_scanb<<<1, 512, 0, stream>>>(bsum, nchunks);
    k_scanc<<<nchunks, 512, 0, stream>>>(dcnt, bsum, rowptr, cursor, N, E);
    k_scatter<<<eBlocks, 256, 0, stream>>>(src, dst, et, cursor, packed, E);

    // ---- layer 0 ----
    k_hb<128><<<hbBlocks, 192, 0, stream>>>(x, V0, loop0, b0, hb, h0, N);
    k_pull0<<<pullBlocks, 256, 0, stream>>>(rowptr, packed, comb0, hb, h0, N);

    // ---- layer 1 ----
    k_pull_u<<<pullBlocks, 256, 0, stream>>>(rowptr, packed, comb1, h0, hb, N);
    k_post<<<postBlocks, 256, 0, stream>>>(hb, h0, V1, loop1, b1, h1, N);

    // ---- layer 2 ----
    k_pull_u<<<pullBlocks, 256, 0, stream>>>(rowptr, packed, comb2, h1, hb, N);
    k_post<<<postBlocks, 256, 0, stream>>>(hb, h1, V2, loop2, b2, h2, N);

    // ---- heads + reparameterization ----
    k_mlp<<<mlpBlocks, 256, 0, stream>>>(h0, h1, h2, Wm1, bm1, Wm2, bm2,
                                         Ws1, bs1, Ws2, bs2, noise, z, N);
    // ---- outputs ----
    k_pairs<<<(U * 64 + 255) / 256, 256, 0, stream>>>(z, ui, ii, out, U, T);
    k_preds<<<(T * 64 + 255) / 256, 256, 0, stream>>>(z, tes, ted, out, U, T);
}